// Round 7
// baseline (116.349 us; speedup 1.0000x reference)
//
#include <hip/hip_runtime.h>
#include <hip/hip_fp16.h>

// PhotometricLoss: total = 0.8*L1 + 0.2*DSSIM; fused separable 11x11 Gaussian
// SSIM, SAME zero padding. Inputs BHWC fp32 (B=4,H=1080,W=1920,C=3).
// R7: phase-1b fused across all 4 planes (read-all -> 1 barrier -> write-all
// -> 1 barrier): block barriers 10 -> 4, 16-deep ds_read ILP. LDS 14.8KB,
// 8 blocks/CU.

typedef _Float16 h2_t __attribute__((ext_vector_type(2)));

#define TW 32
#define TH 32
#define IH 42         // tile rows incl halo
#define NPAIR 21      // column pairs (42 cols)
#define SPW 22        // sP row stride in uints (88B rows, b64-aligned)
#define PLANE 924     // IH*SPW uints per plane
#define HTR 44        // h-conv region row stride in halves (88B, b64-aligned)
#define NSLOT 512

#define HH 1080
#define WW 1920
#define GX 180        // (WW/TW)*3 channels
#define GY 34         // ceil(HH/TH)

// Gaussian(sigma=1.5, 11 taps), normalized; matches fp32 reference within ~2e-7
static constexpr float G[11] = {
    0.00102838f, 0.00759876f, 0.03600077f, 0.10936069f, 0.21300554f,
    0.26601174f, 0.21300554f, 0.10936069f, 0.03600077f, 0.00759876f,
    0.00102838f};

#define WV(m) (((m) >= 0 && (m) <= 10) ? G[((m) < 0) ? 0 : (((m) > 10) ? 10 : (m))] : 0.0f)

struct f4u { float x, y, z, w; } __attribute__((packed, aligned(4)));

__device__ __forceinline__ unsigned short f2hbits(float x) {
    return __half_as_ushort(__float2half(x));
}
__device__ __forceinline__ unsigned int pkrtz(float a, float b) {
    return __builtin_bit_cast(unsigned int, __builtin_amdgcn_cvt_pkrtz(a, b));
}
__device__ __forceinline__ float dot2h(unsigned int a, unsigned int b, float c) {
#if __has_builtin(__builtin_amdgcn_fdot2)
    return __builtin_amdgcn_fdot2(__builtin_bit_cast(h2_t, a),
                                  __builtin_bit_cast(h2_t, b), c, false);
#else
    h2_t ah = __builtin_bit_cast(h2_t, a), bh = __builtin_bit_cast(h2_t, b);
    return c + (float)ah[0] * (float)bh[0] + (float)ah[1] * (float)bh[1];
#endif
}

// horizontal 11-tap conv of one plane, one item = (row, 4 output cols)
__device__ __forceinline__ void h_item(const unsigned* __restrict__ spq,
                                       int t, float a[4]) {
    int r  = t >> 3;
    int p0 = (t & 7) << 1;                 // starting column pair (even)
    const unsigned* sp = spq + r * SPW + p0;
    uint2 d0 = *(const uint2*)&sp[0];
    uint2 d1 = *(const uint2*)&sp[2];
    uint2 d2 = *(const uint2*)&sp[4];
    unsigned e = sp[6];
    unsigned pr[7] = {d0.x, d0.y, d1.x, d1.y, d2.x, d2.y, e};
    a[0] = a[1] = a[2] = a[3] = 0.f;
    #pragma unroll
    for (int u = 0; u < 4; ++u) {
        #pragma unroll
        for (int p = 0; p < 7; ++p) {
            const float w0 = WV(2 * p - u), w1 = WV(2 * p + 1 - u);
            if (w0 != 0.f || w1 != 0.f) {
                const unsigned gwc = (unsigned)f2hbits(w0) |
                                     ((unsigned)f2hbits(w1) << 16);
                a[u] = dot2h(pr[p], gwc, a[u]);
            }
        }
    }
}
__device__ __forceinline__ void h_write(unsigned short* __restrict__ hq,
                                        int t, const float a[4]) {
    int r  = t >> 3;
    int cb = (t & 7) << 2;
    #pragma unroll
    for (int u = 0; u < 4; ++u) hq[(cb + u) * HTR + r] = f2hbits(a[u]);
}

__global__ __launch_bounds__(256, 8) void photo_main(
    const float* __restrict__ xin, const float* __restrict__ yin,
    double* __restrict__ accum, int B, int nwg)
{
    __shared__ unsigned int sPbuf[4 * PLANE];   // 14784 B; planes aliased in-place
    __shared__ float red[8];

    // ---- bijective XCD swizzle (nwg % 8 == 0), channel fastest in x
    int orig = blockIdx.x + GX * (blockIdx.y + GY * blockIdx.z);
    int nid = ((nwg & 7) == 0) ? ((orig & 7) * (nwg >> 3) + (orig >> 3)) : orig;
    int bx   = nid % GX;
    int rest = nid / GX;
    int by   = rest % GY;
    int b    = rest / GY;
    int c    = bx % 3;
    int tx   = bx / 3;
    const int row0 = by * TH, col0 = tx * TW;
    const int tid  = threadIdx.x;
    const int imgbase = b * (HH * WW * 3) + c;

    // ---- Phase 1a: stage 4 packed fp16 moment planes {x,y,x2+y2,xy} over the
    // 42x42 halo tile; fold L1 over the central 32x32.
    float l1_sum = 0.f;
    const bool interior = (tx >= 1) && (tx <= 58) && (by >= 1) && (by <= 32);
    if (interior) {
        for (int i = tid; i < IH * NPAIR; i += 256) {
            int r  = i / NPAIR;
            int pc = i - r * NPAIR;
            int gr  = row0 - 5 + r;
            int gc0 = col0 - 5 + 2 * pc;
            int base = imgbase + (gr * WW + gc0) * 3;
            f4u vx = *(const f4u*)&xin[base];     // x0 = .x, x1 = .w (stride-3)
            f4u vy = *(const f4u*)&yin[base];
            float x0 = vx.x, x1 = vx.w, y0 = vy.x, y1 = vy.w;
            sPbuf[0 * PLANE + r * SPW + pc] = pkrtz(x0, x1);
            sPbuf[1 * PLANE + r * SPW + pc] = pkrtz(y0, y1);
            sPbuf[2 * PLANE + r * SPW + pc] =
                pkrtz(x0 * x0 + y0 * y0, x1 * x1 + y1 * y1);
            sPbuf[3 * PLANE + r * SPW + pc] = pkrtz(x0 * y0, x1 * y1);
            if (r >= 5 && r < 5 + TH) {
                if (pc >= 3 && pc <= 18) l1_sum += fabsf(x0 - y0);
                if (pc >= 2 && pc <= 17) l1_sum += fabsf(x1 - y1);
            }
        }
    } else {
        #pragma unroll 1
        for (int i = tid; i < IH * NPAIR; i += 256) {
            int r  = i / NPAIR;
            int pc = i - r * NPAIR;
            int gr  = row0 - 5 + r;
            int gc0 = col0 - 5 + 2 * pc;
            bool rin = (unsigned)gr < (unsigned)HH;
            bool c0  = rin && ((unsigned)gc0       < (unsigned)WW);
            bool c1  = rin && ((unsigned)(gc0 + 1) < (unsigned)WW);
            int base = imgbase + (gr * WW + gc0) * 3;
            float x0 = 0.f, x1 = 0.f, y0 = 0.f, y1 = 0.f;
            if (c0) { x0 = xin[base];     y0 = yin[base]; }
            if (c1) { x1 = xin[base + 3]; y1 = yin[base + 3]; }
            sPbuf[0 * PLANE + r * SPW + pc] = pkrtz(x0, x1);
            sPbuf[1 * PLANE + r * SPW + pc] = pkrtz(y0, y1);
            sPbuf[2 * PLANE + r * SPW + pc] =
                pkrtz(x0 * x0 + y0 * y0, x1 * x1 + y1 * y1);
            sPbuf[3 * PLANE + r * SPW + pc] = pkrtz(x0 * y0, x1 * y1);
            if (r >= 5 && r < 5 + TH) {
                if (c0 && pc >= 3 && pc <= 18) l1_sum += fabsf(x0 - y0);
                if (c1 && pc >= 2 && pc <= 17) l1_sum += fabsf(x1 - y1);
            }
        }
    }
    __syncthreads();

    // ---- Phase 1b (fused): h-conv ALL 4 planes to registers, one barrier,
    // write all results over their own plane storage (transposed fp16), one
    // barrier. 336 items on 256 threads: item tid, plus tid+256 iff tid < 80.
    {
        const bool has2 = tid < (IH * 8 - 256);
        float A0[4][4], A1[4][4];
        #pragma unroll
        for (int q = 0; q < 4; ++q) h_item(&sPbuf[q * PLANE], tid, A0[q]);
        if (has2) {
            #pragma unroll
            for (int q = 0; q < 4; ++q) h_item(&sPbuf[q * PLANE], tid + 256, A1[q]);
        }
        __syncthreads();
        #pragma unroll
        for (int q = 0; q < 4; ++q)
            h_write((unsigned short*)&sPbuf[q * PLANE], tid, A0[q]);
        if (has2) {
            #pragma unroll
            for (int q = 0; q < 4; ++q)
                h_write((unsigned short*)&sPbuf[q * PLANE], tid + 256, A1[q]);
        }
        __syncthreads();
    }

    // ---- Phase 2: vertical conv via dot2 on contiguous row pairs + SSIM.
    const float C1c = 1e-4f, C2c = 9e-4f;
    float ssim_sum = 0.f;
    {
        int cc = tid & 31;
        int rb = (tid >> 5) << 2;
        float acc[4][4];                 // [u][q]
        #pragma unroll
        for (int u = 0; u < 4; ++u)
            #pragma unroll
            for (int q = 0; q < 4; ++q) acc[u][q] = 0.f;
        #pragma unroll
        for (int q = 0; q < 4; ++q) {
            const unsigned short* hq = (const unsigned short*)&sPbuf[q * PLANE];
            const unsigned short* hp = &hq[cc * HTR + rb];
            uint2 d0 = *(const uint2*)&hp[0];
            uint2 d1 = *(const uint2*)&hp[4];
            uint2 d2 = *(const uint2*)&hp[8];
            unsigned e = *(const unsigned*)&hp[12];
            unsigned pr[7] = {d0.x, d0.y, d1.x, d1.y, d2.x, d2.y, e};
            #pragma unroll
            for (int u = 0; u < 4; ++u) {
                #pragma unroll
                for (int p = 0; p < 7; ++p) {
                    const float w0 = WV(2 * p - u), w1 = WV(2 * p + 1 - u);
                    if (w0 != 0.f || w1 != 0.f) {
                        const unsigned gwc = (unsigned)f2hbits(w0) |
                                             ((unsigned)f2hbits(w1) << 16);
                        acc[u][q] = dot2h(pr[p], gwc, acc[u][q]);
                    }
                }
            }
        }
        #pragma unroll
        for (int u = 0; u < 4; ++u) {
            int gr = row0 + rb + u;
            if (gr < HH) {               // cols always in range (WW % 32 == 0)
                float mu1 = acc[u][0], mu2 = acc[u][1];
                float mu1s = mu1 * mu1, mu2s = mu2 * mu2, mu12 = mu1 * mu2;
                float ssum = acc[u][2] - mu1s - mu2s;   // sigma1^2 + sigma2^2
                float s12  = acc[u][3] - mu12;
                float num = (2.f * mu12 + C1c) * (2.f * s12 + C2c);
                float den = (mu1s + mu2s + C1c) * (ssum + C2c);
                ssim_sum += num * __builtin_amdgcn_rcpf(den);
            }
        }
    }

    // ---- Block reduction, then hashed double atomics
    #pragma unroll
    for (int off = 32; off > 0; off >>= 1) {
        ssim_sum += __shfl_down(ssim_sum, off);
        l1_sum   += __shfl_down(l1_sum, off);
    }
    int wave = tid >> 6;
    if ((tid & 63) == 0) { red[wave] = ssim_sum; red[4 + wave] = l1_sum; }
    __syncthreads();
    if (tid == 0) {
        float s = red[0] + red[1] + red[2] + red[3];
        float l = red[4] + red[5] + red[6] + red[7];
        double* slot = accum + (size_t)(orig & (NSLOT - 1)) * 2;
        atomicAdd(&slot[0], (double)l);
        atomicAdd(&slot[1], (double)s);
    }
}

__global__ __launch_bounds__(NSLOT) void photo_final(
    const double* __restrict__ accum, float* __restrict__ out, double invN)
{
    __shared__ double sl[8], ss[8];
    int tid = threadIdx.x;
    double l = accum[tid * 2 + 0];
    double s = accum[tid * 2 + 1];
    #pragma unroll
    for (int off = 32; off > 0; off >>= 1) {
        l += __shfl_down(l, off);
        s += __shfl_down(s, off);
    }
    if ((tid & 63) == 0) { sl[tid >> 6] = l; ss[tid >> 6] = s; }
    __syncthreads();
    if (tid == 0) {
        double L = 0.0, S = 0.0;
        #pragma unroll
        for (int i = 0; i < NSLOT / 64; ++i) { L += sl[i]; S += ss[i]; }
        double l1    = L * invN;
        double ssim  = S * invN;
        double dssim = (1.0 - ssim) * 0.5;
        out[0] = (float)(0.8 * l1 + 0.2 * dssim);
        out[1] = (float)l1;
        out[2] = (float)dssim;
    }
}

extern "C" void kernel_launch(void* const* d_in, const int* in_sizes, int n_in,
                              void* d_out, int out_size, void* d_ws, size_t ws_size,
                              hipStream_t stream)
{
    const int H = 1080, W = 1920, C = 3;
    const float* x = (const float*)d_in[0];
    const float* y = (const float*)d_in[1];
    int B = in_sizes[0] / (H * W * C);

    double* accum = (double*)d_ws;
    hipMemsetAsync(d_ws, 0, NSLOT * 2 * sizeof(double), stream);

    dim3 grid(GX, GY, B);
    int nwg = GX * GY * B;
    photo_main<<<grid, dim3(256), 0, stream>>>(x, y, accum, B, nwg);

    double invN = 1.0 / ((double)B * H * W * C);
    photo_final<<<1, NSLOT, 0, stream>>>(accum, (float*)d_out, invN);
}